// Round 3
// baseline (156.159 us; speedup 1.0000x reference)
//
#include <hip/hip_runtime.h>

#define TWO_PI_F 6.283185307179586f
#define EPS_F 1e-6f
#define LOG2E_F 1.4426950408889634f
#define BATCH 32

// Bare v_exp_f32 (2^x). libm exp2f wraps it with edge-case fixups (round-11
// measured: -11 us on layer 2 from dropping the wrapper).
#if __has_builtin(__builtin_amdgcn_exp2f)
#define EXP2F(x) __builtin_amdgcn_exp2f(x)
#else
#define EXP2F(x) exp2f(x)
#endif

typedef float v2f __attribute__((ext_vector_type(2)));

// Replace non-finite by 0 (bit test so fast-math can't fold it away).
__device__ __forceinline__ float sane(float x) {
    return ((__float_as_uint(x) & 0x7f800000u) == 0x7f800000u) ? 0.f : x;
}

// ============================================================================
// Monolithic fused layer (round-2 form): used for L1 and L3 (controls).
// ============================================================================
template<int LO, int LI, int ND, int NK, int NCOMP, int KOUT,
         int KP, int TPG, int G, bool FIRST>
__global__ __launch_bounds__(TPG*G) void layer_kernel(
    const float* __restrict__ in_x,            // FIRST: (B,1,64,7) f32
    const float* __restrict__ prev_sel,        // !FIRST: (B,LI,ND,7) f32
    const float* __restrict__ prev_tot,        // !FIRST: (B,LI) f32
    const float* __restrict__ kern,            // (LO,LI,NK,7) f32
    const float* __restrict__ bias,            // (LO,) f32
    float* __restrict__ out_sel,               // (B,LO,KOUT,7) f32
    float* __restrict__ out_tot)               // (B,LO) f32
{
    constexpr int KUSE   = NCOMP / KP;
    static_assert(KUSE * KP == NCOMP, "exact k tiling required");
    constexpr int NT     = TPG * G;
    constexpr int CHUNK  = (NCOMP + G - 1) / G;
    constexpr int NPADT  = G*CHUNK + 4;        // padded poly-table length
    constexpr int NCOMP4 = (NCOMP + 3) & ~3;
    constexpr int NQn    = NCOMP4 / 4;
    constexpr int NPAIR  = KP / 2;
    constexpr int PPAD   = NPAIR > 0 ? NPAIR : 1;
    constexpr bool ODD   = (KP & 1) != 0;

    const int b   = blockIdx.x / LO;
    const int lo  = blockIdx.x % LO;
    const int tid = threadIdx.x;
    const int g   = tid / TPG;
    const int kt  = tid % TPG;
    const bool active = (kt < KUSE);

    struct StageT {
        float4 d_c[LI*ND];
        float4 k_c[LI*NK];
        float  d_w[LI*ND], d_px[LI*ND], d_py[LI*ND];
        float  k_w[LI*NK], k_px[LI*NK], k_py[LI*NK];
    };
    constexpr size_t ACCB = (size_t)(G > 1 ? (G-1)*TPG*KP : 1) * sizeof(float);
    constexpr size_t UB   = sizeof(StageT) > ACCB ? sizeof(StageT) : ACCB;
    __shared__ __align__(16) unsigned char u_smem[UB];
    StageT& st    = *reinterpret_cast<StageT*>(u_smem);
    float* accbuf = reinterpret_cast<float*>(u_smem);

    __shared__ float2 cPos[NCOMP];
    __shared__ float4 nP[NPADT];
    __shared__ float4 nQ[NPADT];
    __shared__ float4 cC[NCOMP];
    __shared__ float  w2s[NCOMP];
    __shared__ __align__(16) float a2s[NCOMP4];
    __shared__ __align__(16) float scr[64];
    __shared__ float  selint[32];
    __shared__ float  dscale[LI];
    __shared__ float  ptot[FIRST ? 1 : BATCH*LI];

    if constexpr (FIRST) {
        if (tid < ND) {
            const float* s = in_x + (size_t)(b*ND + tid)*7;
            const float w  = sane(s[0]);
            const float c0 = sane(s[3]), c1 = sane(s[4]), c2 = sane(s[5]), c3 = sane(s[6]);
            st.d_w[tid] = w; st.d_px[tid] = sane(s[1]); st.d_py[tid] = sane(s[2]);
            st.d_c[tid] = make_float4(c0, c1, c2, c3);
            const float det = c0*c3 - c1*c2;
            scr[tid] = sane(fabsf(w) * TWO_PI_F * sqrtf(fmaxf(det, EPS_F)));
        }
        __syncthreads();
        if (tid == 0) {
            float s = 0.f;
            const float4* s4 = (const float4*)scr;
            for (int i = 0; i < 16; ++i) {
                const float4 v = s4[i];
                s += v.x; s += v.y; s += v.z; s += v.w;
            }
            dscale[0] = 1.f / (s + EPS_F);
        }
        __syncthreads();
        if (tid < ND) st.d_w[tid] = sane(st.d_w[tid] * dscale[0]);
    } else {
        for (int i = tid; i < BATCH*LI; i += NT) ptot[i] = prev_tot[i];
        __syncthreads();
        if (tid < LI) {
            float s = 0.f;
            #pragma unroll 1
            for (int bb = 0; bb < BATCH; ++bb) s += ptot[bb*LI + tid];
            dscale[tid] = 1.f / (s / (float)BATCH + EPS_F);
        }
        __syncthreads();
        if (tid < LI*ND) {
            const int li = tid / ND;
            const float* s = prev_sel + (size_t)(b*LI*ND + tid)*7;
            st.d_w[tid]  = sane(s[0] * dscale[li]);
            st.d_px[tid] = s[1]; st.d_py[tid] = s[2];
            st.d_c[tid]  = make_float4(s[3], s[4], s[5], s[6]);
        }
    }
    if (tid < LI*NK) {
        const float* s = kern + (size_t)(lo*LI*NK + tid)*7;
        st.k_w[tid]  = sane(s[0]);
        st.k_px[tid] = sane(s[1]); st.k_py[tid] = sane(s[2]);
        st.k_c[tid]  = make_float4(sane(s[3]), sane(s[4]), sane(s[5]), sane(s[6]));
    }
    __syncthreads();

    if (tid < NCOMP) {
        const int li = tid / (ND*NK);
        const int r  = tid % (ND*NK);
        const int nd = r / NK, nk = r % NK;
        const int di = li*ND + nd, ki = li*NK + nk;
        const float4 dc = st.d_c[di], kc = st.k_c[ki];
        const float c0 = dc.x + kc.x, c1 = dc.y + kc.y, c2 = dc.z + kc.z, c3 = dc.w + kc.w;
        const float dd = dc.x*dc.w - dc.y*dc.z;
        const float dk = kc.x*kc.w - kc.y*kc.z;
        const float ds = c0*c3 - c1*c2;
        const float w  = sane(st.d_w[di]*st.k_w[ki]*TWO_PI_F*sqrtf(fmaxf(dd*dk, 0.f) / fmaxf(ds, EPS_F)));
        const float px = sane(st.d_px[di] + st.k_px[ki]);
        const float py = sane(st.d_py[di] + st.k_py[ki]);
        const float inv = -0.5f * LOG2E_F / ds;
        const float a   = sane(c3*inv);
        const float bb  = sane(-(c1 + c2)*inv);
        const float cc  = sane(c0*inv);
        const float dd2 = sane(-(2.f*a*px + bb*py));
        const float ee  = sane(-(2.f*cc*py + bb*px));
        const float ff  = sane((a*px + bb*py)*px + cc*py*py);
        cPos[tid] = make_float2(px, py);
        nP[tid]   = make_float4(a, bb, cc, dd2);
        nQ[tid]   = make_float4(ee, ff, w, 0.f);
        cC[tid]   = make_float4(sane(c0), sane(c1), sane(c2), sane(c3));
    }
    for (int i = NCOMP + tid; i < NPADT; i += NT) {
        nP[i] = make_float4(0.f, 0.f, 0.f, 0.f);
        nQ[i] = make_float4(0.f, 0.f, 0.f, 0.f);
    }
    __syncthreads();

    v2f kxP[PPAD], kyP[PPAD], kx2P[PPAD], ky2P[PPAD], kxyP[PPAD], accP[PPAD];
    float kxS = 0.f, kyS = 0.f, kx2S = 0.f, ky2S = 0.f, kxyS = 0.f, accS = 0.f;
    #pragma unroll
    for (int p = 0; p < NPAIR; ++p) {
        float x0 = 0.f, y0 = 0.f, x1 = 0.f, y1 = 0.f;
        if (active) {
            const float2 p0 = cPos[kt + (2*p    )*KUSE];
            const float2 p1 = cPos[kt + (2*p + 1)*KUSE];
            x0 = p0.x; y0 = p0.y; x1 = p1.x; y1 = p1.y;
        }
        v2f kx; kx.x = x0; kx.y = x1;
        v2f ky; ky.x = y0; ky.y = y1;
        kxP[p] = kx; kyP[p] = ky;
        kx2P[p] = kx*kx; ky2P[p] = ky*ky; kxyP[p] = kx*ky;
        v2f z; z.x = 0.f; z.y = 0.f; accP[p] = z;
    }
    if constexpr (ODD) {
        if (active) { const float2 pz = cPos[kt + (KP-1)*KUSE]; kxS = pz.x; kyS = pz.y; }
        kx2S = kxS*kxS; ky2S = kyS*kyS; kxyS = kxS*kyS;
    }
    {
        const int n0 = g*CHUNK;
        const float4* __restrict__ bP = &nP[n0];
        const float4* __restrict__ bQ = &nQ[n0];
        float4 P0 = bP[0], Q0 = bQ[0];
        float4 P1 = bP[1], Q1 = bQ[1];
        float4 P2 = bP[2], Q2 = bQ[2];
        float4 P3 = bP[3], Q3 = bQ[3];
        int nr = 4;

#define PHB_STEP(PP,QQ)                                                       \
        {   const float4 Pn_ = bP[nr], Qn_ = bQ[nr]; ++nr;                    \
            v2f Pa; Pa.x = PP.x; Pa.y = PP.x;                                 \
            v2f Pb; Pb.x = PP.y; Pb.y = PP.y;                                 \
            v2f Pc; Pc.x = PP.z; Pc.y = PP.z;                                 \
            v2f Pd; Pd.x = PP.w; Pd.y = PP.w;                                 \
            v2f Qe; Qe.x = QQ.x; Qe.y = QQ.x;                                 \
            v2f Qf; Qf.x = QQ.y; Qf.y = QQ.y;                                 \
            v2f Qw; Qw.x = QQ.z; Qw.y = QQ.z;                                 \
            _Pragma("unroll")                                                 \
            for (int p = 0; p < NPAIR; ++p) {                                 \
                const v2f md = __builtin_elementwise_fma(Pa, kx2P[p],         \
                               __builtin_elementwise_fma(Pb, kxyP[p],         \
                               __builtin_elementwise_fma(Pc, ky2P[p],         \
                               __builtin_elementwise_fma(Pd, kxP[p],          \
                               __builtin_elementwise_fma(Qe, kyP[p], Qf)))));  \
                v2f ex; ex.x = EXP2F(md.x); ex.y = EXP2F(md.y);               \
                accP[p] = __builtin_elementwise_fma(Qw, ex, accP[p]);         \
            }                                                                 \
            if constexpr (ODD) {                                              \
                const float md = fmaf(PP.x, kx2S,                             \
                                 fmaf(PP.y, kxyS,                             \
                                 fmaf(PP.z, ky2S,                             \
                                 fmaf(PP.w, kxS,                              \
                                 fmaf(QQ.x, kyS, QQ.y)))));                   \
                accS = fmaf(QQ.z, EXP2F(md), accS);                           \
            }                                                                 \
            PP = Pn_; QQ = Qn_; }

        #pragma unroll 1
        for (int i4 = 0; i4 < CHUNK/4; ++i4) {
            PHB_STEP(P0, Q0)
            PHB_STEP(P1, Q1)
            PHB_STEP(P2, Q2)
            PHB_STEP(P3, Q3)
        }
        if constexpr ((CHUNK % 4) >= 1) PHB_STEP(P0, Q0)
        if constexpr ((CHUNK % 4) >= 2) PHB_STEP(P1, Q1)
        if constexpr ((CHUNK % 4) >= 3) PHB_STEP(P2, Q2)
#undef PHB_STEP
    }
    float acc[KP];
    #pragma unroll
    for (int p = 0; p < NPAIR; ++p) { acc[2*p] = accP[p].x; acc[2*p+1] = accP[p].y; }
    if constexpr (ODD) acc[KP-1] = accS;

    if (g > 0 && active) {
        #pragma unroll
        for (int j = 0; j < KP; ++j) accbuf[((g-1)*TPG + kt)*KP + j] = acc[j];
    }
    __syncthreads();

    const float bi = bias[lo];
    if (g == 0 && active) {
        #pragma unroll
        for (int j = 0; j < KP; ++j) {
            float s = acc[j];
            for (int gg = 1; gg < G; ++gg) s += accbuf[((gg-1)*TPG + kt)*KP + j];
            const float v  = s + bi;
            const float sc = fmaxf(v, 0.f) / (fabsf(v) + EPS_F);
            const int   k  = kt + j*KUSE;
            const float ww = sane(nQ[k].z * sc);
            w2s[k] = ww;
            a2s[k] = fabsf(ww);
        }
    }
    if constexpr (NCOMP4 > NCOMP) {
        if (tid >= NCOMP && tid < NCOMP4) a2s[tid] = -1.f;
    }
    __syncthreads();

    constexpr int CQ = (NQn + G - 1) / G;
    int rank[KP];
    float myv[KP];
    #pragma unroll
    for (int j = 0; j < KP; ++j) rank[j] = 0;
    if (active) {
        #pragma unroll
        for (int j = 0; j < KP; ++j) myv[j] = a2s[kt + j*KUSE];
        const int q0 = g*CQ;
        const int q1 = (q0 + CQ < NQn) ? (q0 + CQ) : NQn;
        for (int q = q0; q < q1; ++q) {
            const float4 v4 = ((const float4*)a2s)[q];
            #pragma unroll
            for (int c = 0; c < 4; ++c) {
                const float vj = (c == 0) ? v4.x : (c == 1) ? v4.y : (c == 2) ? v4.z : v4.w;
                const int   jj = 4*q + c;
                #pragma unroll
                for (int j = 0; j < KP; ++j) {
                    const int myk = kt + j*KUSE;
                    rank[j] += (vj > myv[j] || (vj == myv[j] && jj < myk)) ? 1 : 0;
                }
            }
        }
        if (g > 0) {
            #pragma unroll
            for (int j = 0; j < KP; ++j) accbuf[((g-1)*TPG + kt)*KP + j] = (float)rank[j];
        }
    }
    __syncthreads();

    if (g == 0 && active) {
        #pragma unroll
        for (int j = 0; j < KP; ++j) {
            int r = rank[j];
            for (int gg = 1; gg < G; ++gg) r += (int)accbuf[((gg-1)*TPG + kt)*KP + j];
            if (r < KOUT) {
                const int k = kt + j*KUSE;
                const float2 p = cPos[k];
                const float4 c = cC[k];
                const float ww = w2s[k];
                float* dst = out_sel + (size_t)((b*LO + lo)*KOUT + r)*7;
                dst[0] = ww; dst[1] = p.x; dst[2] = p.y;
                dst[3] = c.x; dst[4] = c.y; dst[5] = c.z; dst[6] = c.w;
                const float det = c.x*c.w - c.y*c.z;
                selint[r] = sane(fabsf(ww) * TWO_PI_F * sqrtf(fmaxf(det, EPS_F)));
            }
        }
    }
    __syncthreads();
    if (tid == 0) {
        float s = 0.f;
        for (int i = 0; i < KOUT; ++i) s += selint[i];
        out_tot[b*LO + lo] = s;
    }
}

// ============================================================================
// Split-layer pair (round-3 experiment, applied to L2 only):
// layer_partial: NSPLIT blocks per (b,lo); each runs phase-pre + Phase A
// (duplicated, deterministic) + Phase B for G/NSPLIT of the n-groups, and
// writes per-GROUP partial sums to gpart (f32 round-trip -> exact). Block
// s==0 also writes the per-comp table {w,px,py,C} for the finalize kernel.
// No fences/atomics: the kernel boundary is the sync (round-1 lesson).
// ============================================================================
template<int LO, int LI, int ND, int NK, int NCOMP,
         int KP, int TPG, int G, int NSPLIT, bool FIRST>
__global__ __launch_bounds__(TPG*(G/NSPLIT)) void layer_partial(
    const float* __restrict__ in_x,
    const float* __restrict__ prev_sel,
    const float* __restrict__ prev_tot,
    const float* __restrict__ kern,
    float* __restrict__ comp7,   // (B*LO, NCOMP, 8): w,px,py,C00 | C01,C10,C11,0
    float* __restrict__ gpart)   // (B*LO, G, GSTR)
{
    constexpr int KUSE  = NCOMP / KP;
    static_assert(KUSE * KP == NCOMP, "exact k tiling required");
    static_assert(G % NSPLIT == 0, "split along group boundaries");
    constexpr int GBLK  = G / NSPLIT;
    constexpr int NT    = TPG * GBLK;
    constexpr int CHUNK = (NCOMP + G - 1) / G;
    constexpr int NPADT = G*CHUNK + 4;
    constexpr int GSTR  = (NCOMP + 7) & ~7;
    constexpr int NPAIR = KP / 2;
    constexpr int PPAD  = NPAIR > 0 ? NPAIR : 1;
    constexpr bool ODD  = (KP & 1) != 0;
    static_assert(NT >= LI*ND && NT >= LI*NK && NT >= LI, "one-pass staging");

    const int s    = blockIdx.x % NSPLIT;
    const int unit = blockIdx.x / NSPLIT;
    const int lo   = unit % LO;
    const int b    = unit / LO;
    const int tid  = threadIdx.x;
    const int gl   = tid / TPG;
    const int gg   = s*GBLK + gl;       // GLOBAL group id -> same n-range
    const int kt   = tid % TPG;
    const bool active = (kt < KUSE);

    __shared__ struct {
        float4 d_c[LI*ND];
        float4 k_c[LI*NK];
        float  d_w[LI*ND], d_px[LI*ND], d_py[LI*ND];
        float  k_w[LI*NK], k_px[LI*NK], k_py[LI*NK];
    } st;
    __shared__ float2 cPos[NCOMP];
    __shared__ float4 nP[NPADT];
    __shared__ float4 nQ[NPADT];
    __shared__ __align__(16) float scr[64];
    __shared__ float dscale[LI];
    __shared__ float ptot[FIRST ? 1 : BATCH*LI];

    if constexpr (FIRST) {
        if (tid < ND) {
            const float* sp = in_x + (size_t)(b*ND + tid)*7;
            const float w  = sane(sp[0]);
            const float c0 = sane(sp[3]), c1 = sane(sp[4]), c2 = sane(sp[5]), c3 = sane(sp[6]);
            st.d_w[tid] = w; st.d_px[tid] = sane(sp[1]); st.d_py[tid] = sane(sp[2]);
            st.d_c[tid] = make_float4(c0, c1, c2, c3);
            const float det = c0*c3 - c1*c2;
            scr[tid] = sane(fabsf(w) * TWO_PI_F * sqrtf(fmaxf(det, EPS_F)));
        }
        __syncthreads();
        if (tid == 0) {
            float ssum = 0.f;
            const float4* s4 = (const float4*)scr;
            for (int i = 0; i < 16; ++i) {
                const float4 v = s4[i];
                ssum += v.x; ssum += v.y; ssum += v.z; ssum += v.w;
            }
            dscale[0] = 1.f / (ssum + EPS_F);
        }
        __syncthreads();
        if (tid < ND) st.d_w[tid] = sane(st.d_w[tid] * dscale[0]);
    } else {
        for (int i = tid; i < BATCH*LI; i += NT) ptot[i] = prev_tot[i];
        __syncthreads();
        if (tid < LI) {
            float ssum = 0.f;
            #pragma unroll 1
            for (int bb = 0; bb < BATCH; ++bb) ssum += ptot[bb*LI + tid];
            dscale[tid] = 1.f / (ssum / (float)BATCH + EPS_F);
        }
        __syncthreads();
        if (tid < LI*ND) {
            const int li = tid / ND;
            const float* sp = prev_sel + (size_t)(b*LI*ND + tid)*7;
            st.d_w[tid]  = sane(sp[0] * dscale[li]);
            st.d_px[tid] = sp[1]; st.d_py[tid] = sp[2];
            st.d_c[tid]  = make_float4(sp[3], sp[4], sp[5], sp[6]);
        }
    }
    if (tid < LI*NK) {
        const float* sp = kern + (size_t)(lo*LI*NK + tid)*7;
        st.k_w[tid]  = sane(sp[0]);
        st.k_px[tid] = sane(sp[1]); st.k_py[tid] = sane(sp[2]);
        st.k_c[tid]  = make_float4(sane(sp[3]), sane(sp[4]), sane(sp[5]), sane(sp[6]));
    }
    __syncthreads();

    for (int i = tid; i < NCOMP; i += NT) {
        const int li = i / (ND*NK);
        const int rr = i % (ND*NK);
        const int nd = rr / NK, nk = rr % NK;
        const int di = li*ND + nd, ki = li*NK + nk;
        const float4 dc = st.d_c[di], kc = st.k_c[ki];
        const float c0 = dc.x + kc.x, c1 = dc.y + kc.y, c2 = dc.z + kc.z, c3 = dc.w + kc.w;
        const float dd = dc.x*dc.w - dc.y*dc.z;
        const float dk = kc.x*kc.w - kc.y*kc.z;
        const float ds = c0*c3 - c1*c2;
        const float w  = sane(st.d_w[di]*st.k_w[ki]*TWO_PI_F*sqrtf(fmaxf(dd*dk, 0.f) / fmaxf(ds, EPS_F)));
        const float px = sane(st.d_px[di] + st.k_px[ki]);
        const float py = sane(st.d_py[di] + st.k_py[ki]);
        const float inv = -0.5f * LOG2E_F / ds;
        const float a   = sane(c3*inv);
        const float bb  = sane(-(c1 + c2)*inv);
        const float cc  = sane(c0*inv);
        const float dd2 = sane(-(2.f*a*px + bb*py));
        const float ee  = sane(-(2.f*cc*py + bb*px));
        const float ff  = sane((a*px + bb*py)*px + cc*py*py);
        cPos[i] = make_float2(px, py);
        nP[i]   = make_float4(a, bb, cc, dd2);
        nQ[i]   = make_float4(ee, ff, w, 0.f);
        if (s == 0) {   // comp table for finalize (one writer per unit)
            float* c7 = comp7 + ((size_t)unit*NCOMP + i)*8;
            *(float4*)c7       = make_float4(w, px, py, sane(c0));
            *(float4*)(c7 + 4) = make_float4(sane(c1), sane(c2), sane(c3), 0.f);
        }
    }
    for (int i = NCOMP + tid; i < NPADT; i += NT) {
        nP[i] = make_float4(0.f, 0.f, 0.f, 0.f);
        nQ[i] = make_float4(0.f, 0.f, 0.f, 0.f);
    }
    __syncthreads();

    v2f kxP[PPAD], kyP[PPAD], kx2P[PPAD], ky2P[PPAD], kxyP[PPAD], accP[PPAD];
    float kxS = 0.f, kyS = 0.f, kx2S = 0.f, ky2S = 0.f, kxyS = 0.f, accS = 0.f;
    #pragma unroll
    for (int p = 0; p < NPAIR; ++p) {
        float x0 = 0.f, y0 = 0.f, x1 = 0.f, y1 = 0.f;
        if (active) {
            const float2 p0 = cPos[kt + (2*p    )*KUSE];
            const float2 p1 = cPos[kt + (2*p + 1)*KUSE];
            x0 = p0.x; y0 = p0.y; x1 = p1.x; y1 = p1.y;
        }
        v2f kx; kx.x = x0; kx.y = x1;
        v2f ky; ky.x = y0; ky.y = y1;
        kxP[p] = kx; kyP[p] = ky;
        kx2P[p] = kx*kx; ky2P[p] = ky*ky; kxyP[p] = kx*ky;
        v2f z; z.x = 0.f; z.y = 0.f; accP[p] = z;
    }
    if constexpr (ODD) {
        if (active) { const float2 pz = cPos[kt + (KP-1)*KUSE]; kxS = pz.x; kyS = pz.y; }
        kx2S = kxS*kxS; ky2S = kyS*kyS; kxyS = kxS*kyS;
    }
    {
        const int n0 = gg*CHUNK;
        const float4* __restrict__ bP = &nP[n0];
        const float4* __restrict__ bQ = &nQ[n0];
        float4 P0 = bP[0], Q0 = bQ[0];
        float4 P1 = bP[1], Q1 = bQ[1];
        float4 P2 = bP[2], Q2 = bQ[2];
        float4 P3 = bP[3], Q3 = bQ[3];
        int nr = 4;

#define PHB_STEP(PP,QQ)                                                       \
        {   const float4 Pn_ = bP[nr], Qn_ = bQ[nr]; ++nr;                    \
            v2f Pa; Pa.x = PP.x; Pa.y = PP.x;                                 \
            v2f Pb; Pb.x = PP.y; Pb.y = PP.y;                                 \
            v2f Pc; Pc.x = PP.z; Pc.y = PP.z;                                 \
            v2f Pd; Pd.x = PP.w; Pd.y = PP.w;                                 \
            v2f Qe; Qe.x = QQ.x; Qe.y = QQ.x;                                 \
            v2f Qf; Qf.x = QQ.y; Qf.y = QQ.y;                                 \
            v2f Qw; Qw.x = QQ.z; Qw.y = QQ.z;                                 \
            _Pragma("unroll")                                                 \
            for (int p = 0; p < NPAIR; ++p) {                                 \
                const v2f md = __builtin_elementwise_fma(Pa, kx2P[p],         \
                               __builtin_elementwise_fma(Pb, kxyP[p],         \
                               __builtin_elementwise_fma(Pc, ky2P[p],         \
                               __builtin_elementwise_fma(Pd, kxP[p],          \
                               __builtin_elementwise_fma(Qe, kyP[p], Qf)))));  \
                v2f ex; ex.x = EXP2F(md.x); ex.y = EXP2F(md.y);               \
                accP[p] = __builtin_elementwise_fma(Qw, ex, accP[p]);         \
            }                                                                 \
            if constexpr (ODD) {                                              \
                const float md = fmaf(PP.x, kx2S,                             \
                                 fmaf(PP.y, kxyS,                             \
                                 fmaf(PP.z, ky2S,                             \
                                 fmaf(PP.w, kxS,                              \
                                 fmaf(QQ.x, kyS, QQ.y)))));                   \
                accS = fmaf(QQ.z, EXP2F(md), accS);                           \
            }                                                                 \
            PP = Pn_; QQ = Qn_; }

        #pragma unroll 1
        for (int i4 = 0; i4 < CHUNK/4; ++i4) {
            PHB_STEP(P0, Q0)
            PHB_STEP(P1, Q1)
            PHB_STEP(P2, Q2)
            PHB_STEP(P3, Q3)
        }
        if constexpr ((CHUNK % 4) >= 1) PHB_STEP(P0, Q0)
        if constexpr ((CHUNK % 4) >= 2) PHB_STEP(P1, Q1)
        if constexpr ((CHUNK % 4) >= 3) PHB_STEP(P2, Q2)
#undef PHB_STEP
    }
    float acc[KP];
    #pragma unroll
    for (int p = 0; p < NPAIR; ++p) { acc[2*p] = accP[p].x; acc[2*p+1] = accP[p].y; }
    if constexpr (ODD) acc[KP-1] = accS;

    // Per-GROUP partials to global; coalesced across kt. No fence needed:
    // the consumer is a separate kernel.
    if (active) {
        float* gp = gpart + ((size_t)unit*G + gg)*GSTR;
        #pragma unroll
        for (int j = 0; j < KP; ++j) gp[kt + j*KUSE] = acc[j];
    }
}

// Finalize: sum the G group partials in the EXACT sequential order of the
// monolithic kernel (bit-identical), bias + relu_fit scale, stable rank,
// select + write sel/tot.
template<int LO, int NCOMP, int KOUT, int G, int NTC>
__global__ __launch_bounds__(NTC) void layer_finalize(
    const float* __restrict__ comp7,  // (B*LO, NCOMP, 8)
    const float* __restrict__ gpart,  // (B*LO, G, GSTR)
    const float* __restrict__ bias,
    float* __restrict__ out_sel,      // (B*LO, KOUT, 7)
    float* __restrict__ out_tot)      // (B*LO)
{
    constexpr int GSTR   = (NCOMP + 7) & ~7;
    constexpr int NCOMP4 = (NCOMP + 3) & ~3;
    constexpr int NQn    = NCOMP4 / 4;
    const int unit = blockIdx.x;
    const int lo   = unit % LO;
    const int tid  = threadIdx.x;

    __shared__ float w2s[NCOMP];
    __shared__ __align__(16) float a2s[NCOMP4];
    __shared__ float selint[32];

    const float bi = bias[lo];
    const float* gb = gpart + (size_t)unit*G*GSTR;
    for (int k = tid; k < NCOMP; k += NTC) {
        float ssum = gb[k];
        #pragma unroll 1
        for (int gg = 1; gg < G; ++gg) ssum += gb[(size_t)gg*GSTR + k];
        const float v  = ssum + bi;
        const float sc = fmaxf(v, 0.f) / (fabsf(v) + EPS_F);
        const float ww = sane(comp7[((size_t)unit*NCOMP + k)*8] * sc);
        w2s[k] = ww;
        a2s[k] = fabsf(ww);
    }
    for (int i = NCOMP + tid; i < NCOMP4; i += NTC) a2s[i] = -1.f;
    __syncthreads();

    for (int k = tid; k < NCOMP; k += NTC) {
        const float mv = a2s[k];
        int r = 0;
        for (int q = 0; q < NQn; ++q) {
            const float4 v4 = ((const float4*)a2s)[q];  // LDS broadcast
            const int j4 = 4*q;
            r += (v4.x > mv || (v4.x == mv && j4     < k)) ? 1 : 0;
            r += (v4.y > mv || (v4.y == mv && j4 + 1 < k)) ? 1 : 0;
            r += (v4.z > mv || (v4.z == mv && j4 + 2 < k)) ? 1 : 0;
            r += (v4.w > mv || (v4.w == mv && j4 + 3 < k)) ? 1 : 0;
        }
        if (r < KOUT) {
            const float4 c0 = *(const float4*)&comp7[((size_t)unit*NCOMP + k)*8];
            const float4 c1 = *(const float4*)&comp7[((size_t)unit*NCOMP + k)*8 + 4];
            const float ww = w2s[k];
            float* dst = out_sel + (size_t)(unit*KOUT + r)*7;
            dst[0] = ww; dst[1] = c0.y; dst[2] = c0.z;
            dst[3] = c0.w; dst[4] = c1.x; dst[5] = c1.y; dst[6] = c1.z;
            const float det = c0.w*c1.z - c1.x*c1.y;
            selint[r] = sane(fabsf(ww) * TWO_PI_F * sqrtf(fmaxf(det, EPS_F)));
        }
    }
    __syncthreads();
    if (tid == 0) {
        float ssum = 0.f;
        for (int i = 0; i < KOUT; ++i) ssum += selint[i];
        out_tot[unit] = ssum;
    }
}

// Final: batchnorm3 scale (mean over batch) -> integrate -> log_softmax -> f32
__global__ __launch_bounds__(64) void final_kernel(
    const float* __restrict__ sel3,   // (B,10,5,7)
    const float* __restrict__ tot3,   // (B,10)
    float* __restrict__ out)          // (B,10) f32
{
    const int b = blockIdx.x;
    const int tid = threadIdx.x;
    __shared__ float scale3[10], integ[10], red2[2];
    if (tid < 10) {
        float s = 0.f;
        for (int bb = 0; bb < BATCH; ++bb) s += tot3[bb*10 + tid];
        scale3[tid] = 1.f / (s / (float)BATCH + EPS_F);
    }
    __syncthreads();
    if (tid < 10) {
        float s = 0.f;
        const float* base = sel3 + (size_t)((b*10 + tid)*5)*7;
        for (int kk = 0; kk < 5; ++kk) {
            const float* c = base + kk*7;
            const float det = c[3]*c[6] - c[4]*c[5];
            s += c[0] * scale3[tid] * TWO_PI_F * sqrtf(fmaxf(det, EPS_F));
        }
        integ[tid] = sane(s);
    }
    __syncthreads();
    if (tid == 0) {
        float m = -1e30f;
        for (int l = 0; l < 10; ++l) m = fmaxf(m, integ[l]);
        float ss = 0.f;
        for (int l = 0; l < 10; ++l) ss += __expf(integ[l] - m);
        red2[0] = m; red2[1] = logf(ss);
    }
    __syncthreads();
    if (tid < 10) out[b*10 + tid] = integ[tid] - red2[0] - red2[1];
}

extern "C" void kernel_launch(void* const* d_in, const int* in_sizes, int n_in,
                              void* d_out, int out_size, void* d_ws, size_t ws_size,
                              hipStream_t stream)
{
    const float* in_x = (const float*)d_in[0];
    const float* k1   = (const float*)d_in[1];
    const float* k2   = (const float*)d_in[2];
    const float* k3   = (const float*)d_in[3];
    const float* b1   = (const float*)d_in[4];
    const float* b2   = (const float*)d_in[5];
    const float* b3   = (const float*)d_in[6];
    float* out = (float*)d_out;   // reference output dtype is float32

    float* ws = (float*)d_ws;
    float* sel1 = ws;                  // 32*5*25*7  = 28000 floats
    float* tot1 = ws + 28000;          // 160
    float* sel2 = ws + 28160;          // 32*6*12*7  = 16128
    float* tot2 = ws + 44288;          // 192
    float* sel3 = ws + 44480;          // 32*10*5*7  = 11200
    float* tot3 = ws + 55680;          // 320
    float* comp7_2 = ws + 56000;       // 192*625*8  = 960000
    float* gpart2  = ws + 1016000;     // 192*8*632  = 970752  (~7.9 MB total)

    // Layer 1 (control, round-2 form): 320 comps, keep 25. TPG=64,G=16.
    layer_kernel<5, 1, 64, 5, 320, 25, 5, 64, 16, true><<<BATCH*5, 1024, 0, stream>>>(
        in_x, nullptr, nullptr, k1, b1, sel1, tot1);
    // Layer 2 SPLIT: partial = 192 units x NSPLIT=4 -> 768 blocks x 256 thr
    // (3 blocks/CU exactly, ~30 KB LDS each, 12 waves/CU machine-wide).
    layer_partial<6, 5, 25, 5, 625, 5, 128, 8, 4, false>
        <<<BATCH*6*4, 256, 0, stream>>>(nullptr, sel1, tot1, k2, comp7_2, gpart2);
    // Finalize: 192 blocks x 640 thr (one k per thread), bit-exact group-order
    // sum + rank + select.
    layer_finalize<6, 625, 12, 8, 640><<<BATCH*6, 640, 0, stream>>>(
        comp7_2, gpart2, b2, sel2, tot2);
    // Layer 3 (control, round-2 form): 360 comps, keep 5. TPG=64,G=12.
    layer_kernel<10, 6, 12, 5, 360, 5, 6, 64, 12, false><<<BATCH*10, 768, 0, stream>>>(
        nullptr, sel2, tot2, k3, b3, sel3, tot3);
    // Final: batchnorm + integrate + log_softmax.
    final_kernel<<<BATCH, 64, 0, stream>>>(sel3, tot3, out);
}

// Round 4
// 142.704 us; speedup vs baseline: 1.0943x; 1.0943x over previous
//
#include <hip/hip_runtime.h>

#define TWO_PI_F 6.283185307179586f
#define EPS_F 1e-6f
#define LOG2E_F 1.4426950408889634f
#define BATCH 32

// Bare v_exp_f32 (2^x). libm exp2f wraps it with edge-case fixups (round-11
// measured: -11 us on layer 2 from dropping the wrapper).
#if __has_builtin(__builtin_amdgcn_exp2f)
#define EXP2F(x) __builtin_amdgcn_exp2f(x)
#else
#define EXP2F(x) exp2f(x)
#endif

typedef float v2f __attribute__((ext_vector_type(2)));

// Replace non-finite by 0 (bit test so fast-math can't fold it away).
__device__ __forceinline__ float sane(float x) {
    return ((__float_as_uint(x) & 0x7f800000u) == 0x7f800000u) ? 0.f : x;
}

// One fused layer: [prev batchnorm] -> gm_convolve -> eval_at_centers
// (polynomial form, k-slots paired for v_pk_fma_f32, 4-deep pipelined LDS
// broadcast) -> relu_fit (stable-rank top-KOUT) -> selected comps + integral.
//
// Round-16: the post-Phase-B reduction (G-way accumulator sum + relu/w2s) and
// the rank finalize + select-write are now one-thread-per-component across
// ALL waves (was: serialized on group 0's 1-2 waves while 10-14 waves idled
// at barriers). Sum order over g is ascending, identical to the old g0 loop
// -> bit-exact. Rank partials are integers -> order-free.
// Round-14/15 lessons: no cross-block fences/atomics (buffer_wbl2 storms);
// 4-deep named-register Phase-B pipeline (42 us vs 48 on layer 2).
template<int LO, int LI, int ND, int NK, int NCOMP, int KOUT,
         int KP, int TPG, int G, bool FIRST>
__global__ __launch_bounds__(TPG*G) void layer_kernel(
    const float* __restrict__ in_x,            // FIRST: (B,1,64,7) f32
    const float* __restrict__ prev_sel,        // !FIRST: (B,LI,ND,7) f32
    const float* __restrict__ prev_tot,        // !FIRST: (B,LI) f32
    const float* __restrict__ kern,            // (LO,LI,NK,7) f32
    const float* __restrict__ bias,            // (LO,) f32
    float* __restrict__ out_sel,               // (B,LO,KOUT,7) f32
    float* __restrict__ out_tot)               // (B,LO) f32
{
    constexpr int KUSE   = NCOMP / KP;
    static_assert(KUSE * KP == NCOMP, "exact k tiling required");
    constexpr int NT     = TPG * G;
    static_assert(NT >= NCOMP, "one k per thread in reduce/select phases");
    constexpr int CHUNK  = (NCOMP + G - 1) / G;
    constexpr int NPADT  = G*CHUNK + 4;        // padded poly-table length
    constexpr int NCOMP4 = (NCOMP + 3) & ~3;
    constexpr int NQn    = NCOMP4 / 4;
    constexpr int NPAIR  = KP / 2;
    constexpr int PPAD   = NPAIR > 0 ? NPAIR : 1;
    constexpr bool ODD   = (KP & 1) != 0;

    const int b   = blockIdx.x / LO;
    const int lo  = blockIdx.x % LO;
    const int tid = threadIdx.x;
    const int g   = tid / TPG;
    const int kt  = tid % TPG;
    const bool active = (kt < KUSE);

    // Staging arrays (dead after Phase A) union'd with accbuf (live Phase B+).
    // accbuf now holds ALL G groups' partials: (g*TPG + kt)*KP + j.
    struct StageT {
        float4 d_c[LI*ND];
        float4 k_c[LI*NK];
        float  d_w[LI*ND], d_px[LI*ND], d_py[LI*ND];
        float  k_w[LI*NK], k_px[LI*NK], k_py[LI*NK];
    };
    constexpr size_t ACCB = (size_t)G*TPG*KP * sizeof(float);
    constexpr size_t UB   = sizeof(StageT) > ACCB ? sizeof(StageT) : ACCB;
    __shared__ __align__(16) unsigned char u_smem[UB];
    StageT& st    = *reinterpret_cast<StageT*>(u_smem);
    float* accbuf = reinterpret_cast<float*>(u_smem);

    __shared__ float2 cPos[NCOMP];  // px, py
    __shared__ float4 nP[NPADT];    // a, b, c, d (log2e-folded quadform poly)
    __shared__ float4 nQ[NPADT];    // e, f, w, 0
    __shared__ float4 cC[NCOMP];    // C00,C01,C10,C11
    __shared__ float  w2s[NCOMP];
    __shared__ __align__(16) float a2s[NCOMP4];
    __shared__ __align__(16) float scr[64];
    __shared__ float  selint[32];
    __shared__ float  dscale[LI];
    __shared__ float  ptot[FIRST ? 1 : BATCH*LI];

    // ---- Phase pre: incoming batchnorm + stage data/kernel into LDS
    if constexpr (FIRST) {
        if (tid < ND) {
            const float* s = in_x + (size_t)(b*ND + tid)*7;
            const float w  = sane(s[0]);
            const float c0 = sane(s[3]), c1 = sane(s[4]), c2 = sane(s[5]), c3 = sane(s[6]);
            st.d_w[tid] = w; st.d_px[tid] = sane(s[1]); st.d_py[tid] = sane(s[2]);
            st.d_c[tid] = make_float4(c0, c1, c2, c3);
            const float det = c0*c3 - c1*c2;
            scr[tid] = sane(fabsf(w) * TWO_PI_F * sqrtf(fmaxf(det, EPS_F)));
        }
        __syncthreads();
        if (tid == 0) {
            // float4 reads, scalar adds in same left-to-right order (bit-exact)
            float s = 0.f;
            const float4* s4 = (const float4*)scr;
            for (int i = 0; i < 16; ++i) {
                const float4 v = s4[i];
                s += v.x; s += v.y; s += v.z; s += v.w;
            }
            dscale[0] = 1.f / (s + EPS_F);
        }
        __syncthreads();
        if (tid < ND) st.d_w[tid] = sane(st.d_w[tid] * dscale[0]);
    } else {
        // Cooperative coalesced stage of prev_tot, then order-preserving sum
        // from LDS (kills the 32-deep strided global-load latency chain).
        for (int i = tid; i < BATCH*LI; i += NT) ptot[i] = prev_tot[i];
        __syncthreads();
        if (tid < LI) {
            float s = 0.f;
            #pragma unroll 1
            for (int bb = 0; bb < BATCH; ++bb) s += ptot[bb*LI + tid];
            dscale[tid] = 1.f / (s / (float)BATCH + EPS_F);
        }
        __syncthreads();
        if (tid < LI*ND) {
            const int li = tid / ND;
            const float* s = prev_sel + (size_t)(b*LI*ND + tid)*7;
            st.d_w[tid]  = sane(s[0] * dscale[li]);
            st.d_px[tid] = s[1]; st.d_py[tid] = s[2];
            st.d_c[tid]  = make_float4(s[3], s[4], s[5], s[6]);
        }
    }
    if (tid < LI*NK) {
        const float* s = kern + (size_t)(lo*LI*NK + tid)*7;
        st.k_w[tid]  = sane(s[0]);
        st.k_px[tid] = sane(s[1]); st.k_py[tid] = sane(s[2]);
        st.k_c[tid]  = make_float4(sane(s[3]), sane(s[4]), sane(s[5]), sane(s[6]));
    }
    __syncthreads();

    // ---- Phase A: gm_convolve -> poly coefficients in LDS.
    // Flattening matches reference reshape: (li, nd, nk), nk fastest.
    if (tid < NCOMP) {
        const int li = tid / (ND*NK);
        const int r  = tid % (ND*NK);
        const int nd = r / NK, nk = r % NK;
        const int di = li*ND + nd, ki = li*NK + nk;
        const float4 dc = st.d_c[di], kc = st.k_c[ki];
        const float c0 = dc.x + kc.x, c1 = dc.y + kc.y, c2 = dc.z + kc.z, c3 = dc.w + kc.w;
        const float dd = dc.x*dc.w - dc.y*dc.z;
        const float dk = kc.x*kc.w - kc.y*kc.z;
        const float ds = c0*c3 - c1*c2;
        const float w  = sane(st.d_w[di]*st.k_w[ki]*TWO_PI_F*sqrtf(fmaxf(dd*dk, 0.f) / fmaxf(ds, EPS_F)));
        const float px = sane(st.d_px[di] + st.k_px[ki]);
        const float py = sane(st.d_py[di] + st.k_py[ki]);
        const float inv = -0.5f * LOG2E_F / ds;
        const float a   = sane(c3*inv);
        const float bb  = sane(-(c1 + c2)*inv);
        const float cc  = sane(c0*inv);
        const float dd2 = sane(-(2.f*a*px + bb*py));
        const float ee  = sane(-(2.f*cc*py + bb*px));
        const float ff  = sane((a*px + bb*py)*px + cc*py*py);
        cPos[tid] = make_float2(px, py);
        nP[tid]   = make_float4(a, bb, cc, dd2);
        nQ[tid]   = make_float4(ee, ff, w, 0.f);
        cC[tid]   = make_float4(sane(c0), sane(c1), sane(c2), sane(c3));
    }
    // Zero pad rows: w=0 -> term contributes +0.0 (bitwise-neutral in acc).
    for (int i = NCOMP + tid; i < NPADT; i += NT) {
        nP[i] = make_float4(0.f, 0.f, 0.f, 0.f);
        nQ[i] = make_float4(0.f, 0.f, 0.f, 0.f);
    }
    __syncthreads();

    // ---- Phase B: eval_at_centers. k-slots paired (v_pk_fma_f32); per-n LDS
    // broadcast software-pipelined 4 deep with named registers (all pipeline
    // indices compile-time -> no scratch). Consumption order n0..n0+CHUNK-1
    // is unchanged -> bit-exact accumulation.
    v2f kxP[PPAD], kyP[PPAD], kx2P[PPAD], ky2P[PPAD], kxyP[PPAD], accP[PPAD];
    float kxS = 0.f, kyS = 0.f, kx2S = 0.f, ky2S = 0.f, kxyS = 0.f, accS = 0.f;
    #pragma unroll
    for (int p = 0; p < NPAIR; ++p) {
        float x0 = 0.f, y0 = 0.f, x1 = 0.f, y1 = 0.f;
        if (active) {
            const float2 p0 = cPos[kt + (2*p    )*KUSE];
            const float2 p1 = cPos[kt + (2*p + 1)*KUSE];
            x0 = p0.x; y0 = p0.y; x1 = p1.x; y1 = p1.y;
        }
        v2f kx; kx.x = x0; kx.y = x1;
        v2f ky; ky.x = y0; ky.y = y1;
        kxP[p] = kx; kyP[p] = ky;
        kx2P[p] = kx*kx; ky2P[p] = ky*ky; kxyP[p] = kx*ky;
        v2f z; z.x = 0.f; z.y = 0.f; accP[p] = z;
    }
    if constexpr (ODD) {
        if (active) { const float2 pz = cPos[kt + (KP-1)*KUSE]; kxS = pz.x; kyS = pz.y; }
        kx2S = kxS*kxS; ky2S = kyS*kyS; kxyS = kxS*kyS;
    }
    {
        const int n0 = g*CHUNK;
        const float4* __restrict__ bP = &nP[n0];
        const float4* __restrict__ bQ = &nQ[n0];
        float4 P0 = bP[0], Q0 = bQ[0];
        float4 P1 = bP[1], Q1 = bQ[1];
        float4 P2 = bP[2], Q2 = bQ[2];
        float4 P3 = bP[3], Q3 = bQ[3];
        int nr = 4;   // next prefetch (rel); pad rows make bP[CHUNK..CHUNK+3] safe

#define PHB_STEP(PP,QQ)                                                       \
        {   const float4 Pn_ = bP[nr], Qn_ = bQ[nr]; ++nr;                    \
            v2f Pa; Pa.x = PP.x; Pa.y = PP.x;                                 \
            v2f Pb; Pb.x = PP.y; Pb.y = PP.y;                                 \
            v2f Pc; Pc.x = PP.z; Pc.y = PP.z;                                 \
            v2f Pd; Pd.x = PP.w; Pd.y = PP.w;                                 \
            v2f Qe; Qe.x = QQ.x; Qe.y = QQ.x;                                 \
            v2f Qf; Qf.x = QQ.y; Qf.y = QQ.y;                                 \
            v2f Qw; Qw.x = QQ.z; Qw.y = QQ.z;                                 \
            _Pragma("unroll")                                                 \
            for (int p = 0; p < NPAIR; ++p) {                                 \
                const v2f md = __builtin_elementwise_fma(Pa, kx2P[p],         \
                               __builtin_elementwise_fma(Pb, kxyP[p],         \
                               __builtin_elementwise_fma(Pc, ky2P[p],         \
                               __builtin_elementwise_fma(Pd, kxP[p],          \
                               __builtin_elementwise_fma(Qe, kyP[p], Qf)))));  \
                v2f ex; ex.x = EXP2F(md.x); ex.y = EXP2F(md.y);               \
                accP[p] = __builtin_elementwise_fma(Qw, ex, accP[p]);         \
            }                                                                 \
            if constexpr (ODD) {                                              \
                const float md = fmaf(PP.x, kx2S,                             \
                                 fmaf(PP.y, kxyS,                             \
                                 fmaf(PP.z, ky2S,                             \
                                 fmaf(PP.w, kxS,                              \
                                 fmaf(QQ.x, kyS, QQ.y)))));                   \
                accS = fmaf(QQ.z, EXP2F(md), accS);                           \
            }                                                                 \
            PP = Pn_; QQ = Qn_; }

        #pragma unroll 1
        for (int i4 = 0; i4 < CHUNK/4; ++i4) {
            PHB_STEP(P0, Q0)
            PHB_STEP(P1, Q1)
            PHB_STEP(P2, Q2)
            PHB_STEP(P3, Q3)
        }
        if constexpr ((CHUNK % 4) >= 1) PHB_STEP(P0, Q0)
        if constexpr ((CHUNK % 4) >= 2) PHB_STEP(P1, Q1)
        if constexpr ((CHUNK % 4) >= 3) PHB_STEP(P2, Q2)
#undef PHB_STEP
    }
    // Unpack pairs back to per-slot acc[]
    float acc[KP];
    #pragma unroll
    for (int p = 0; p < NPAIR; ++p) { acc[2*p] = accP[p].x; acc[2*p+1] = accP[p].y; }
    if constexpr (ODD) acc[KP-1] = accS;

    // ALL groups (incl. g0) publish partials; reduce is then fully parallel.
    if (active) {
        #pragma unroll
        for (int j = 0; j < KP; ++j) accbuf[(g*TPG + kt)*KP + j] = acc[j];
    }
    __syncthreads();

    // ---- Phase R: per-component G-way sum (ascending g == old g0 order,
    // bit-exact) + bias + relu_fit scale. One thread per component.
    const float bi = bias[lo];
    if (tid < NCOMP) {
        const int kt2 = tid % KUSE;
        const int j2  = tid / KUSE;
        float s = accbuf[(kt2)*KP + j2];
        #pragma unroll
        for (int g2 = 1; g2 < G; ++g2) s += accbuf[(g2*TPG + kt2)*KP + j2];
        const float v  = s + bi;
        const float sc = fmaxf(v, 0.f) / (fabsf(v) + EPS_F);
        const float ww = sane(nQ[tid].z * sc);
        w2s[tid] = ww;
        a2s[tid] = fabsf(ww);
    }
    if constexpr (NCOMP4 > NCOMP) {
        if (tid >= NCOMP && tid < NCOMP4) a2s[tid] = -1.f;  // pad: never ranks
    }
    __syncthreads();

    // ---- Phase C: stable-descending rank (== jax.lax.top_k order), group-split
    constexpr int CQ = (NQn + G - 1) / G;
    int rank[KP];
    float myv[KP];
    #pragma unroll
    for (int j = 0; j < KP; ++j) rank[j] = 0;
    if (active) {
        #pragma unroll
        for (int j = 0; j < KP; ++j) myv[j] = a2s[kt + j*KUSE];
        const int q0 = g*CQ;
        const int q1 = (q0 + CQ < NQn) ? (q0 + CQ) : NQn;
        for (int q = q0; q < q1; ++q) {
            const float4 v4 = ((const float4*)a2s)[q];  // broadcast
            #pragma unroll
            for (int c = 0; c < 4; ++c) {
                const float vj = (c == 0) ? v4.x : (c == 1) ? v4.y : (c == 2) ? v4.z : v4.w;
                const int   jj = 4*q + c;
                #pragma unroll
                for (int j = 0; j < KP; ++j) {
                    const int myk = kt + j*KUSE;
                    rank[j] += (vj > myv[j] || (vj == myv[j] && jj < myk)) ? 1 : 0;
                }
            }
        }
        // rank partials (ints, <= 625 -> exact in f32) from ALL groups
        #pragma unroll
        for (int j = 0; j < KP; ++j) accbuf[(g*TPG + kt)*KP + j] = (float)rank[j];
    }
    __syncthreads();

    // ---- Phase D: per-component rank finalize + select + write (parallel).
    if (tid < NCOMP) {
        const int kt2 = tid % KUSE;
        const int j2  = tid / KUSE;
        int r = 0;
        #pragma unroll
        for (int g2 = 0; g2 < G; ++g2) r += (int)accbuf[(g2*TPG + kt2)*KP + j2];
        if (r < KOUT) {
            const float2 p = cPos[tid];
            const float4 c = cC[tid];
            const float ww = w2s[tid];
            float* dst = out_sel + (size_t)((b*LO + lo)*KOUT + r)*7;
            dst[0] = ww; dst[1] = p.x; dst[2] = p.y;
            dst[3] = c.x; dst[4] = c.y; dst[5] = c.z; dst[6] = c.w;
            const float det = c.x*c.w - c.y*c.z;
            selint[r] = sane(fabsf(ww) * TWO_PI_F * sqrtf(fmaxf(det, EPS_F)));
        }
    }
    __syncthreads();
    if (tid == 0) {
        float s = 0.f;
        for (int i = 0; i < KOUT; ++i) s += selint[i];
        out_tot[b*LO + lo] = s;
    }
}

// Final: batchnorm3 scale (mean over batch) -> integrate -> log_softmax -> f32
__global__ __launch_bounds__(64) void final_kernel(
    const float* __restrict__ sel3,   // (B,10,5,7)
    const float* __restrict__ tot3,   // (B,10)
    float* __restrict__ out)          // (B,10) f32
{
    const int b = blockIdx.x;
    const int tid = threadIdx.x;
    __shared__ float scale3[10], integ[10], red2[2];
    if (tid < 10) {
        float s = 0.f;
        for (int bb = 0; bb < BATCH; ++bb) s += tot3[bb*10 + tid];
        scale3[tid] = 1.f / (s / (float)BATCH + EPS_F);
    }
    __syncthreads();
    if (tid < 10) {
        float s = 0.f;
        const float* base = sel3 + (size_t)((b*10 + tid)*5)*7;
        for (int kk = 0; kk < 5; ++kk) {
            const float* c = base + kk*7;
            const float det = c[3]*c[6] - c[4]*c[5];
            s += c[0] * scale3[tid] * TWO_PI_F * sqrtf(fmaxf(det, EPS_F));
        }
        integ[tid] = sane(s);
    }
    __syncthreads();
    if (tid == 0) {
        float m = -1e30f;
        for (int l = 0; l < 10; ++l) m = fmaxf(m, integ[l]);
        float ss = 0.f;
        for (int l = 0; l < 10; ++l) ss += __expf(integ[l] - m);
        red2[0] = m; red2[1] = logf(ss);
    }
    __syncthreads();
    if (tid < 10) out[b*10 + tid] = integ[tid] - red2[0] - red2[1];
}

extern "C" void kernel_launch(void* const* d_in, const int* in_sizes, int n_in,
                              void* d_out, int out_size, void* d_ws, size_t ws_size,
                              hipStream_t stream)
{
    const float* in_x = (const float*)d_in[0];
    const float* k1   = (const float*)d_in[1];
    const float* k2   = (const float*)d_in[2];
    const float* k3   = (const float*)d_in[3];
    const float* b1   = (const float*)d_in[4];
    const float* b2   = (const float*)d_in[5];
    const float* b3   = (const float*)d_in[6];
    float* out = (float*)d_out;   // reference output dtype is float32

    float* ws = (float*)d_ws;
    float* sel1 = ws;                  // 32*5*25*7  = 28000 floats
    float* tot1 = ws + 28000;          // 160
    float* sel2 = ws + 28160;          // 32*6*12*7  = 16128
    float* tot2 = ws + 44288;          // 192
    float* sel3 = ws + 44480;          // 32*10*5*7  = 11200
    float* tot3 = ws + 55680;          // 320  (total ~224 KB)

    // Layer 1: 320 comps, keep 25.  KP=5 (64*5=320), TPG=64, G=16 -> NT=1024.
    layer_kernel<5, 1, 64, 5, 320, 25, 5, 64, 16, true><<<BATCH*5, 1024, 0, stream>>>(
        in_x, nullptr, nullptr, k1, b1, sel1, tot1);
    // Layer 2: 625 comps, keep 12.  KP=5 (125*5=625), TPG=128, G=8 -> NT=1024.
    layer_kernel<6, 5, 25, 5, 625, 12, 5, 128, 8, false><<<BATCH*6, 1024, 0, stream>>>(
        nullptr, sel1, tot1, k2, b2, sel2, tot2);
    // Layer 3: 360 comps, keep 5.   KP=6 (60*6=360), TPG=64, G=12 -> NT=768.
    layer_kernel<10, 6, 12, 5, 360, 5, 6, 64, 12, false><<<BATCH*10, 768, 0, stream>>>(
        nullptr, sel2, tot2, k3, b3, sel3, tot3);
    // Final: batchnorm + integrate + log_softmax.
    final_kernel<<<BATCH, 64, 0, stream>>>(sel3, tot3, out);
}